// Round 1
// baseline (533.653 us; speedup 1.0000x reference)
//
#include <hip/hip_runtime.h>
#include <hip/hip_fp16.h>

// Problem constants: B=1, L=2048, C=2048, H=16, D=128, keys = 2L = 4096
#define LQ 2048
#define CDIM 2048
#define NHEAD 16
#define HDIM 128
#define LKEY 4096

typedef _Float16 f16x8 __attribute__((ext_vector_type(8)));
typedef float f32x4 __attribute__((ext_vector_type(4)));

#define GLOAD_LDS16(g, s) __builtin_amdgcn_global_load_lds( \
    (const __attribute__((address_space(1))) void*)(g),     \
    (__attribute__((address_space(3))) void*)(s), 16, 0, 0)

#define MFMA16(a, b, c) __builtin_amdgcn_mfma_f32_16x16x32_f16(a, b, c, 0, 0, 0)

__device__ __forceinline__ void storeC(float* p, float v) { *p = v; }
__device__ __forceinline__ void storeC(__half* p, float v) { *p = __float2half(v); }
__device__ __forceinline__ float toF(float v) { return v; }
__device__ __forceinline__ float toF(__half v) { return __half2float(v); }

// ---------------------------------------------------------------------------
// C[128bm:+128, 128bn:+128] = A[*,0:K] * B[*,0:K]^T  (fp16 in, fp32 acc)
// 128x128 tile, BK=64, 4 waves, 4x4 acc/wave, global_load_lds staging.
// ---------------------------------------------------------------------------
template <typename OutT>
__global__ __launch_bounds__(256, 2) void gemm_bt(
    const __half* __restrict__ A, const __half* __restrict__ B,
    OutT* __restrict__ C, int lda, int ldb, int ldc, int K)
{
    __shared__ __align__(16) __half lA[128 * 64];
    __shared__ __align__(16) __half lB[128 * 64];
    const int tid  = threadIdx.x;
    const int lane = tid & 63;
    const int wave = tid >> 6;
    const int bm = blockIdx.x, bn = blockIdx.y;
    const int r = tid >> 3;     // 0..31: row within 32-row staging slab
    const int g = tid & 7;      // 8-elem col group
    const __half* gA = A + (long)(bm * 128 + r) * lda + ((g ^ (r & 7)) << 3);
    const __half* gB = B + (long)(bn * 128 + r) * ldb + ((g ^ (r & 7)) << 3);
    __half* lAp = lA + tid * 8;
    __half* lBp = lB + tid * 8;
    const int wr = (wave & 1) << 6;
    const int wc = (wave >> 1) << 6;
    const int l15 = lane & 15, quad = lane >> 4;

    f32x4 acc[4][4] = {};

    for (int kt = 0; kt < K; kt += 64) {
#pragma unroll
        for (int i = 0; i < 4; ++i) {
            GLOAD_LDS16(gA + (long)i * 32 * lda, lAp + i * 2048);
            GLOAD_LDS16(gB + (long)i * 32 * ldb, lBp + i * 2048);
        }
        gA += 64; gB += 64;
        __syncthreads();
#pragma unroll
        for (int kk = 0; kk < 2; ++kk) {
            f16x8 af[4], bfr[4];
#pragma unroll
            for (int mi = 0; mi < 4; ++mi) {
                const int m = wr + mi * 16 + l15;
                const int kg = kk * 4 + quad;
                af[mi] = *(const f16x8*)&lA[m * 64 + ((kg ^ (m & 7)) << 3)];
            }
#pragma unroll
            for (int ni = 0; ni < 4; ++ni) {
                const int n = wc + ni * 16 + l15;
                const int kg = kk * 4 + quad;
                bfr[ni] = *(const f16x8*)&lB[n * 64 + ((kg ^ (n & 7)) << 3)];
            }
#pragma unroll
            for (int mi = 0; mi < 4; ++mi)
#pragma unroll
                for (int ni = 0; ni < 4; ++ni)
                    acc[mi][ni] = MFMA16(af[mi], bfr[ni], acc[mi][ni]);
        }
        __syncthreads();
    }
    const int row0 = bm * 128 + wr + quad * 4;
    const int col0 = bn * 128 + wc + l15;
#pragma unroll
    for (int mi = 0; mi < 4; ++mi)
#pragma unroll
        for (int ni = 0; ni < 4; ++ni)
#pragma unroll
            for (int rx = 0; rx < 4; ++rx)
                storeC(&C[(long)(row0 + mi * 16 + rx) * ldc + col0 + ni * 16],
                       acc[mi][ni][rx]);
}

// ---------------------------------------------------------------------------
// Fused attention tile kernel (max-free softmax, log2-domain scores).
// v2: 64 q-rows/block (16/wave), grid (32 q-tiles, 32 = head*2+kc) = 1024
// blocks -> 4 blocks/CU (LDS 32KB: P slab overlays lK after QK; extra
// barrier per step). XCD-affinity swizzle: the 32 blocks sharing one (h,kc)
// K/V chunk (1MB) land on one XCD -> 4 chunks = 4MB = one L2.
// ---------------------------------------------------------------------------
__global__ __launch_bounds__(256, 4) void attn_tile(
    const __half* __restrict__ Qf,  // [2048][2048] normed+roped, log2-scaled
    const __half* __restrict__ Kf,  // kvf [4096][4096]; K in cols 0..2047
    const __half* __restrict__ Vt,  // [2048][4096]  Vt[h*128+d][key]
    float* __restrict__ Opart,      // [2][2048][2048]
    float* __restrict__ lsum)       // [16][2048]
{
    __shared__ __align__(16) __half lK[64 * 128];   // 16 KB (P slab overlays)
    __shared__ __align__(16) __half lV[128 * 64];   // 16 KB

    const int tid  = threadIdx.x;
    const int lane = tid & 63;
    const int wave = tid >> 6;
    const int l15  = lane & 15;
    const int quad = lane >> 4;
    // XCD-affinity remap (bijective on 1024 blocks): blocks with equal hkc
    // have lin = const (mod 32) -> const (mod 8) -> same XCD (round-robin).
    const int lin = blockIdx.y * 32 + blockIdx.x;
    const int hkc = (lin & 7) * 4 + ((lin >> 3) & 3);
    const int qt  = lin >> 5;
    const int h   = hkc >> 1;
    const int kc  = hkc & 1;
    const int q0  = qt * 64 + wave * 16;   // this wave's 16 q-rows

    // Q A-fragments: A[m=l15][k=ks*32+quad*8+j]
    f16x8 aq[4];
#pragma unroll
    for (int ks = 0; ks < 4; ++ks)
        aq[ks] = *(const f16x8*)&Qf[(long)(q0 + l15) * CDIM +
                                    h * HDIM + ks * 32 + quad * 8];

    // staging pointers. LDS[r][g] = global[r][g ^ (r & mask)] (XOR swizzle in
    // the SOURCE address; LDS dest is wave-uniform base + lane*16).
    const int rK = tid >> 4;          // K row 0..15 (+16/issue)
    const int gK = tid & 15;          // 16 groups of 8 halves
    const __half* srcK = Kf + (long)(kc * 2048 + rK) * 4096 + h * HDIM +
                         ((gK ^ (rK & 15)) << 3);
    const int rV = tid >> 3;          // V row (d) 0..31 (+32/issue)
    const int gV = tid & 7;           // 8 groups of 8 halves
    const __half* srcV = Vt + (long)(h * HDIM + rV) * (long)LKEY + kc * 2048 +
                         ((gV ^ (rV & 7)) << 3);
    __half* dstK = lK + tid * 8;
    __half* dstV = lV + tid * 8;
    __half* pW = lK + wave * (16 * 76);   // per-wave P slab, stride 76 halves

    f32x4 accO[8] = {};
    f32x4 l_acc = {};

    for (int st = 0; st < 32; ++st) {
#pragma unroll
        for (int i = 0; i < 4; ++i) {
            GLOAD_LDS16(srcK + (long)(st * 64 + i * 16) * 4096, dstK + i * 2048);
            GLOAD_LDS16(srcV + (long)i * 32 * LKEY + st * 64, dstV + i * 2048);
        }
        __syncthreads();
        // ---- QK^T (acc init -10 folds the exp2 bias) ----
        f32x4 s[4];
#pragma unroll
        for (int nt = 0; nt < 4; ++nt)
            s[nt] = (f32x4){-10.f, -10.f, -10.f, -10.f};
#pragma unroll
        for (int nt = 0; nt < 4; ++nt) {
            const int n = nt * 16 + l15;
#pragma unroll
            for (int ks = 0; ks < 4; ++ks) {
                const f16x8 kf = *(const f16x8*)
                    &lK[n * 128 + (((ks * 4 + quad) ^ (n & 15)) << 3)];
                s[nt] = MFMA16(aq[ks], kf, s[nt]);
            }
        }
        __syncthreads();   // all waves done reading lK before P overlays it
        // ---- P = exp2(s), accumulate l, stage P (per-wave slab in lK) ----
#pragma unroll
        for (int nt = 0; nt < 4; ++nt)
#pragma unroll
            for (int r2 = 0; r2 < 4; ++r2) {
                const float p = __builtin_amdgcn_exp2f(s[nt][r2]);
                l_acc[r2] += p;
                pW[(quad * 4 + r2) * 76 + nt * 16 + l15] = __float2half(p);
            }
        // ---- PV ----
        f16x8 ap0 = *(const f16x8*)&pW[l15 * 76 + quad * 8];
        f16x8 ap1 = *(const f16x8*)&pW[l15 * 76 + 32 + quad * 8];
#pragma unroll
        for (int nt2 = 0; nt2 < 8; ++nt2) {
            const int n2 = nt2 * 16 + l15;
            const f16x8 v0 = *(const f16x8*)&lV[n2 * 64 + ((quad ^ (n2 & 7)) << 3)];
            const f16x8 v1 = *(const f16x8*)&lV[n2 * 64 + (((4 + quad) ^ (n2 & 7)) << 3)];
            accO[nt2] = MFMA16(ap0, v0, accO[nt2]);
            accO[nt2] = MFMA16(ap1, v1, accO[nt2]);
        }
        __syncthreads();   // P reads + lV reads done before next staging
    }

    // ---- l: reduce across the 16 l15 lanes, publish via atomics ----
#pragma unroll
    for (int r2 = 0; r2 < 4; ++r2) {
        float v = l_acc[r2];
        v += __shfl_xor(v, 1);
        v += __shfl_xor(v, 2);
        v += __shfl_xor(v, 4);
        v += __shfl_xor(v, 8);
        if (l15 == 0)
            atomicAdd(&lsum[h * LQ + q0 + quad * 4 + r2], v);
    }
    // ---- O partial (fp32) ----
    float* Cp = Opart + (long)kc * LQ * CDIM + h * HDIM;
#pragma unroll
    for (int nt2 = 0; nt2 < 8; ++nt2)
#pragma unroll
        for (int rx = 0; rx < 4; ++rx)
            Cp[(long)(q0 + quad * 4 + rx) * CDIM + nt2 * 16 + l15] =
                accO[nt2][rx];
}

// ---------------------------------------------------------------------------
// merge: a2[q][c] = (Op0+Op1)[q][c] / lsum[c>>7][q]   (fp16 out)
// ---------------------------------------------------------------------------
__global__ __launch_bounds__(256) void merge_o(
    const float* __restrict__ Op, const float* __restrict__ lsum,
    __half* __restrict__ a2)
{
    const int row = blockIdx.x;
    const int c0  = threadIdx.x * 8;
    const float inv = 1.0f / lsum[(c0 >> 7) * LQ + row];
    const float* p0 = Op + (long)row * CDIM + c0;
    const float* p1 = p0 + (long)LQ * CDIM;
    union { f16x8 v; _Float16 e[8]; } o;
#pragma unroll
    for (int j = 0; j < 8; ++j)
        o.e[j] = (_Float16)((p0[j] + p1[j]) * inv);
    *(f16x8*)&a2[(long)row * 4096 + c0] = o.v;
}

// ---------------------------------------------------------------------------
// In-place per-(row,head) rmsnorm + depth-rope on fp16 data (D=128).
// ---------------------------------------------------------------------------
__global__ __launch_bounds__(256) void norm_rope(
    __half* __restrict__ X, const float* __restrict__ w,
    int stride, int nrows, int kmode, float oscale)
{
    const int gid  = blockIdx.x * 4 + (threadIdx.x >> 6);
    const int lane = threadIdx.x & 63;
    const int row  = gid >> 4;
    const int h    = gid & 15;
    if (row >= nrows) return;
    __half* p = X + (long)row * stride + h * HDIM;
    float x1 = __half2float(p[lane]);
    float x2 = __half2float(p[lane + 64]);
    float ss = x1 * x1 + x2 * x2;
#pragma unroll
    for (int off = 1; off < 64; off <<= 1) ss += __shfl_xor(ss, off);
    const float rn = rsqrtf(ss * (1.0f / 128.0f) + 1e-6f);
    x1 *= rn * w[lane];
    x2 *= rn * w[lane + 64];
    const int depth = kmode ? (row < LQ ? 0 : 1) : 2;
    const float freq = exp2f(-(float)lane * 0.20762050593045702f);
    const float ang = (float)depth * freq;
    float sn, cs;
    __sincosf(ang, &sn, &cs);
    p[lane]      = __float2half((x1 * cs - x2 * sn) * oscale);
    p[lane + 64] = __float2half((x1 * sn + x2 * cs) * oscale);
}

// ---------------------------------------------------------------------------
// helpers
// ---------------------------------------------------------------------------
__global__ void cast_h4(const float* __restrict__ in, __half* __restrict__ out, int n) {
    const int i = (blockIdx.x * 256 + threadIdx.x) << 2;
    if (i >= n) return;
    const float4 v = *(const float4*)&in[i];
    out[i]     = __float2half(v.x);
    out[i + 1] = __float2half(v.y);
    out[i + 2] = __float2half(v.z);
    out[i + 3] = __float2half(v.w);
}

__global__ void cast_wo(const float* __restrict__ in, __half* __restrict__ out) {
    const int idx = blockIdx.x * 256 + threadIdx.x;
    const int o = idx >> 11, c = idx & 2047;
    out[((long)o << 12) + c] = __float2half(in[idx]);
}

template <typename InT>
__global__ __launch_bounds__(256) void transpose_h(
    const InT* __restrict__ in, long inStride, long inOff,
    __half* __restrict__ out, long outStride, long outOff)
{
    __shared__ float t[64][65];
    const long r0 = (long)blockIdx.x * 64;
    const long c0 = (long)blockIdx.y * 64;
    const int tj = threadIdx.x & 63;
    const int ti = threadIdx.x >> 6;
#pragma unroll
    for (int it = 0; it < 16; ++it) {
        const int i = it * 4 + ti;
        t[i][tj] = toF(in[(r0 + i) * inStride + inOff + c0 + tj]);
    }
    __syncthreads();
#pragma unroll
    for (int it = 0; it < 16; ++it) {
        const int i = it * 4 + ti;
        out[(c0 + i) * outStride + outOff + r0 + tj] = __float2half(t[tj][i]);
    }
}

__global__ void sin_feat(const float* __restrict__ sw1, const float* __restrict__ sb1,
                         __half* __restrict__ a2) {
    const int idx = blockIdx.x * 256 + threadIdx.x;
    const int l = idx >> 11, c = idx & 2047;
    const float coord = -1.0f + (2.0f / 2047.0f) * (float)l;
    const float v = sinf(30.0f * (coord * sw1[c] + sb1[c]));
    a2[((long)l << 12) + 2048 + c] = __float2half(v);
}

__global__ __launch_bounds__(256) void final_norm(
    const float* __restrict__ out2, const float* __restrict__ x,
    const float* __restrict__ sb2, const float* __restrict__ on_w,
    float* __restrict__ y)
{
    const int row = blockIdx.x;
    const float* o = out2 + (long)row * CDIM;
    float v[8];
    float ss = 0.f;
#pragma unroll
    for (int i = 0; i < 8; ++i) {
        const int c = threadIdx.x + i * 256;
        const float t = o[c] + sb2[c];
        v[i] = t;
        ss += t * t;
    }
#pragma unroll
    for (int off = 1; off < 64; off <<= 1) ss += __shfl_xor(ss, off);
    __shared__ float red[4];
    const int lane = threadIdx.x & 63, wv = threadIdx.x >> 6;
    if (lane == 0) red[wv] = ss;
    __syncthreads();
    const float tot = red[0] + red[1] + red[2] + red[3];
    const float rn = rsqrtf(tot * (1.0f / 2048.0f) + 1e-6f);
#pragma unroll
    for (int i = 0; i < 8; ++i) {
        const int c = threadIdx.x + i * 256;
        y[(long)row * CDIM + c] = x[(long)row * CDIM + c] + v[i] * rn * on_w[c];
    }
}

// ---------------------------------------------------------------------------
extern "C" void kernel_launch(void* const* d_in, const int* in_sizes, int n_in,
                              void* d_out, int out_size, void* d_ws, size_t ws_size,
                              hipStream_t stream) {
    const float* x    = (const float*)d_in[0];
    const float* h0   = (const float*)d_in[1];
    const float* h1   = (const float*)d_in[2];
    const float* h2   = (const float*)d_in[3];
    const float* Wq   = (const float*)d_in[4];
    const float* Wk   = (const float*)d_in[5];
    const float* Wv   = (const float*)d_in[6];
    const float* Wo   = (const float*)d_in[7];
    const float* qn_w = (const float*)d_in[8];
    const float* kn_w = (const float*)d_in[9];
    const float* on_w = (const float*)d_in[10];
    const float* sw1  = (const float*)d_in[11];
    const float* sb1  = (const float*)d_in[12];
    const float* sw2  = (const float*)d_in[13];
    const float* sb2  = (const float*)d_in[14];
    float* y = (float*)d_out;

    const size_t MB = 1ull << 20;
    char* w = (char*)d_ws;
    __half* xq  = (__half*)(w);             //  8 MB  h2 fp16        (dead after Q gemm)
    __half* xkv = (__half*)(w + 8 * MB);    // 16 MB  [h0;h1] fp16   (dead after KV gemm)
    __half* wqh = (__half*)(w + 24 * MB);   //  8 MB  Wq fp16        (dead after Q gemm)
    __half* wkv = (__half*)(w + 32 * MB);   // 16 MB  [Wk;Wv] fp16   (dead after KV gemm)
    __half* qf  = (__half*)(w + 48 * MB);   //  8 MB  Q proj -> normed q
    __half* kvf = (__half*)(w + 56 * MB);   // 32 MB  [K|V] proj (4096x4096)
    __half* vT  = (__half*)(w + 88 * MB);   // 16 MB  V transposed (2048x4096)
    __half* a2  = (__half*)(w + 104 * MB);  // 16 MB  [attn_out | sin_feat]
    __half* b2  = (__half*)(w + 120 * MB);  // 16 MB  [Wo | sw2^T]
    float* out2 = (float*)(w + 136 * MB);   // 16 MB  final GEMM out
    float* Opart = (float*)(w);             // 32 MB  overlays xq/xkv/wqh (dead)
    float* lsum  = (float*)(w + 32 * MB);   // 128 KB overlays wkv (dead)
    (void)in_sizes; (void)n_in; (void)out_size; (void)ws_size;

    const int n4 = 2048 * 2048;
    cast_h4<<<n4 / 1024, 256, 0, stream>>>(h2, xq, n4);
    cast_h4<<<n4 / 1024, 256, 0, stream>>>(h0, xkv, n4);
    cast_h4<<<n4 / 1024, 256, 0, stream>>>(h1, xkv + n4, n4);
    cast_h4<<<n4 / 1024, 256, 0, stream>>>(Wq, wqh, n4);
    cast_h4<<<n4 / 1024, 256, 0, stream>>>(Wk, wkv, n4);
    cast_h4<<<n4 / 1024, 256, 0, stream>>>(Wv, wkv + n4, n4);
    cast_wo<<<n4 / 256, 256, 0, stream>>>(Wo, b2);
    transpose_h<float><<<dim3(32, 32), 256, 0, stream>>>(sw2, 2048, 0, b2, 4096, 2048);
    sin_feat<<<n4 / 256, 256, 0, stream>>>(sw1, sb1, a2);

    gemm_bt<__half><<<dim3(16, 16), 256, 0, stream>>>(xq, wqh, qf, 2048, 2048, 2048, 2048);
    gemm_bt<__half><<<dim3(32, 32), 256, 0, stream>>>(xkv, wkv, kvf, 2048, 2048, 4096, 2048);

    // q pre-scale = log2(e)/sqrt(D): scores arrive in log2 domain for exp2
    norm_rope<<<8192, 256, 0, stream>>>(qf, qn_w, 2048, 2048, 0, 0.12751743f);
    norm_rope<<<16384, 256, 0, stream>>>(kvf, kn_w, 4096, 4096, 1, 1.0f);
    transpose_h<__half><<<dim3(64, 32), 256, 0, stream>>>(kvf, 4096, 2048, vT, 4096, 0);

    (void)hipMemsetAsync(lsum, 0, NHEAD * LQ * sizeof(float), stream);
    attn_tile<<<dim3(32, 32), 256, 0, stream>>>(qf, kvf, vT, Opart, lsum);
    merge_o<<<2048, 256, 0, stream>>>(Opart, lsum, a2);

    gemm_bt<float><<<dim3(16, 16), 256, 0, stream>>>(a2, b2, out2, 4096, 4096, 2048, 4096);
    final_norm<<<2048, 256, 0, stream>>>(out2, x, sb2, on_w, y);
}